// Round 2
// baseline (8305.470 us; speedup 1.0000x reference)
//
#include <hip/hip_runtime.h>
#include <hip/hip_bf16.h>
#include <stdint.h>

typedef __hip_bfloat16 bf16;
typedef __attribute__((ext_vector_type(8))) short short8;
typedef __attribute__((ext_vector_type(4))) float f32x4;

#define NN 65536
#define DD 512
#define EE 1048576
#define GG 128
#define LL 512

static __device__ __forceinline__ void gld_lds16(const void* g, void* l) {
  __builtin_amdgcn_global_load_lds((const __attribute__((address_space(1))) uint32_t*)g,
                                   (__attribute__((address_space(3))) uint32_t*)l, 16, 0, 0);
}

// ---------------- prep: transpose/cast weights to bf16 ----------------
__global__ __launch_bounds__(256) void k_prep(
    const float* __restrict__ Wc, const float* __restrict__ Wf1, const float* __restrict__ Wf2,
    const float* __restrict__ Wih, const float* __restrict__ Whh,
    bf16* __restrict__ WcT, bf16* __restrict__ Wf1T, bf16* __restrict__ Wf2T,
    bf16* __restrict__ WihB, bf16* __restrict__ WhhB)
{
  const int i = blockIdx.x * 256 + threadIdx.x;
  if (i < 512 * 512) {
    const int k = i >> 9, n = i & 511;
    WcT [n * 512 + k] = __float2bfloat16(Wc [i]);
    Wf1T[n * 512 + k] = __float2bfloat16(Wf1[i]);
    Wf2T[n * 512 + k] = __float2bfloat16(Wf2[i]);
  }
  if (i < 1536 * 512) {
    WihB[i] = __float2bfloat16(Wih[i]);
    WhhB[i] = __float2bfloat16(Whh[i]);
  }
}

// ---------------- CSR build ----------------
__global__ __launch_bounds__(256) void k_deg(const int* __restrict__ dst, int* __restrict__ deg) {
  const int e = blockIdx.x * 256 + threadIdx.x;
  atomicAdd(&deg[dst[e]], 1);
}

// parallel 3-phase exclusive scan of deg[65536]
__global__ __launch_bounds__(1024) void k_scan1(const int* __restrict__ deg,
                                                int* __restrict__ roff, int* __restrict__ partial) {
  __shared__ int sd[1024];
  const int t = threadIdx.x, b = blockIdx.x, i = b * 1024 + t;
  const int v = deg[i];
  sd[t] = v;
  __syncthreads();
  for (int off = 1; off < 1024; off <<= 1) {
    int add = (t >= off) ? sd[t - off] : 0;
    __syncthreads();
    sd[t] += add;
    __syncthreads();
  }
  roff[i] = sd[t] - v;          // exclusive within chunk
  if (t == 1023) partial[b] = sd[t];
}

__global__ __launch_bounds__(64) void k_scan2(const int* __restrict__ partial, int* __restrict__ base) {
  __shared__ int sd[64];
  const int t = threadIdx.x;
  const int v = partial[t];
  sd[t] = v;
  __syncthreads();
  for (int off = 1; off < 64; off <<= 1) {
    int add = (t >= off) ? sd[t - off] : 0;
    __syncthreads();
    sd[t] += add;
    __syncthreads();
  }
  base[t] = sd[t] - v;
  if (t == 63) base[64] = sd[63];
}

__global__ __launch_bounds__(1024) void k_scan3(const int* __restrict__ base,
                                                int* __restrict__ roff, int* __restrict__ cursor) {
  const int b = blockIdx.x, t = threadIdx.x, i = b * 1024 + t;
  const int v = roff[i] + base[b];
  roff[i] = v;
  cursor[i] = v;
  if (i == 0) roff[NN] = base[64];
}

__global__ __launch_bounds__(256) void k_fill(const int* __restrict__ src, const int* __restrict__ dst,
                                              int* __restrict__ cursor, int* __restrict__ csr) {
  const int e = blockIdx.x * 256 + threadIdx.x;
  const int p = atomicAdd(&cursor[dst[e]], 1);
  csr[p] = src[e];
}

// ---------------- mean aggregation: one block per dst node ----------------
__global__ __launch_bounds__(128) void k_agg(
    const float* __restrict__ feats, const int* __restrict__ csr,
    const int* __restrict__ roff, bf16* __restrict__ agg)
{
  const int n = blockIdx.x, t = threadIdx.x;
  const int s0 = roff[n], s1 = roff[n + 1];
  float4 a = make_float4(0.f, 0.f, 0.f, 0.f);
  for (int i = s0; i < s1; ++i) {
    const int s = csr[i];
    const float4 v = *(const float4*)&feats[(long)s * 512 + t * 4];
    a.x += v.x; a.y += v.y; a.z += v.z; a.w += v.w;
  }
  const float sc = 1.f / fmaxf((float)(s1 - s0), 1.f);
  union { bf16 b[4]; ushort4 u; } pk;
  pk.b[0] = __float2bfloat16(a.x * sc);
  pk.b[1] = __float2bfloat16(a.y * sc);
  pk.b[2] = __float2bfloat16(a.z * sc);
  pk.b[3] = __float2bfloat16(a.w * sc);
  *(ushort4*)&agg[(long)n * 512 + t * 4] = pk.u;
}

// ---------------- bf16 GEMM: C[M,Ncols] = A[M,512] @ Bt[Ncols,512]^T + bias ----------------
template<bool GATHER, bool RELU, bool SCATTER>
__global__ __launch_bounds__(256) void k_gemm(
    const bf16* __restrict__ A, const bf16* __restrict__ Bt,
    const float* __restrict__ bias, const int* __restrict__ gidx,
    bf16* __restrict__ outb, float* __restrict__ outf, int Ncols)
{
  __shared__ bf16 lsA[128 * 64];
  __shared__ bf16 lsB[128 * 64];
  const int t = threadIdx.x;
  const int lane = t & 63, wid = t >> 6;
  const int wr = wid >> 1, wc = wid & 1;
  const int tm = blockIdx.y * 128, tn = blockIdx.x * 128;
  const int col8 = (t & 7) * 8;
  const int rsub = t >> 3;
  const int lc = lane & 15, lk = lane >> 4;

  long arow[4], brow[4];
#pragma unroll
  for (int i = 0; i < 4; ++i) {
    const int r = tm + i * 32 + rsub;
    int ar = r;
    if constexpr (GATHER) ar = gidx[r];
    arow[i] = (long)ar * 512;
    brow[i] = (long)(tn + i * 32 + rsub) * 512;
  }

  f32x4 acc[4][4];
#pragma unroll
  for (int a = 0; a < 4; ++a)
#pragma unroll
    for (int b = 0; b < 4; ++b) acc[a][b] = (f32x4){0.f, 0.f, 0.f, 0.f};

  for (int ks = 0; ks < 8; ++ks) {
    const int k0 = ks * 64;
#pragma unroll
    for (int i = 0; i < 4; ++i) {
      gld_lds16(A  + arow[i] + k0 + col8, &lsA[i * 2048 + t * 8]);
      gld_lds16(Bt + brow[i] + k0 + col8, &lsB[i * 2048 + t * 8]);
    }
    __syncthreads();
#pragma unroll
    for (int kk = 0; kk < 2; ++kk) {
      short8 af[4], bfr[4];
#pragma unroll
      for (int mi = 0; mi < 4; ++mi)
        af[mi] = *(const short8*)&lsA[(wr * 64 + mi * 16 + lc) * 64 + kk * 32 + lk * 8];
#pragma unroll
      for (int ni = 0; ni < 4; ++ni)
        bfr[ni] = *(const short8*)&lsB[(wc * 64 + ni * 16 + lc) * 64 + kk * 32 + lk * 8];
#pragma unroll
      for (int mi = 0; mi < 4; ++mi)
#pragma unroll
        for (int ni = 0; ni < 4; ++ni)
          acc[mi][ni] = __builtin_amdgcn_mfma_f32_16x16x32_bf16(af[mi], bfr[ni], acc[mi][ni], 0, 0, 0);
    }
    __syncthreads();
  }

  float bv[4];
#pragma unroll
  for (int ni = 0; ni < 4; ++ni) bv[ni] = bias[tn + wc * 64 + ni * 16 + lc];

#pragma unroll
  for (int mi = 0; mi < 4; ++mi) {
    const int r0 = tm + wr * 64 + mi * 16 + lk * 4;
#pragma unroll
    for (int j = 0; j < 4; ++j) {
      const int row = r0 + j;
      long orow;
      if constexpr (SCATTER) orow = (long)gidx[row] * 512;
      else                   orow = (long)row * Ncols;
#pragma unroll
      for (int ni = 0; ni < 4; ++ni) {
        float v = acc[mi][ni][j] + bv[ni];
        if constexpr (RELU) v = fmaxf(v, 0.f);
        const int c = tn + wc * 64 + ni * 16 + lc;
        if constexpr (SCATTER) outf[orow + c] = v;
        else                   outb[orow + c] = __float2bfloat16(v);
      }
    }
  }
}

// ---------------- persistent GRU ----------------
// 64 blocks = 32 jc (16-col slices) x 2 jm (group halves). 4 waves/block, each
// wave owns one chain of 16 groups for all 512 steps. W_hh fragments live in
// VGPRs (48 x short8 = 192 regs; __launch_bounds__(256,1) -> 512-reg budget).
// h double-buffered by step parity in global; producer waves RELEASE-add a
// per-(chain,step) counter after writing their 16-col slice; consumers poll
// with ACQUIRE loads (device scope handles cross-XCD L2 non-coherence).
// fp32 h carry stays in registers (each lane re-owns the same (g,d) cells).
__global__ __launch_bounds__(256, 1) void k_gru_persist(
    const bf16* __restrict__ Whh, const float* __restrict__ bhh,
    const bf16* __restrict__ gi, bf16* __restrict__ h0, bf16* __restrict__ h1,
    bf16* __restrict__ ys, int* __restrict__ cnt)
{
  const int t = threadIdx.x, lane = t & 63, w = t >> 6;
  const int jm = blockIdx.x >> 5, jc = blockIdx.x & 31;
  const int lc = lane & 15, lk = lane >> 4;
  const int chain = jm * 4 + w;        // 0..7
  const int g0 = chain * 16;           // this wave's 16 groups
  const int d = jc * 16 + lc;          // this lane's output column

  // hoist W_hh fragments into registers: B-frag row = output col (lc), k = kk*32+lk*8
  short8 wf[48];
#pragma unroll
  for (int kk = 0; kk < 16; ++kk)
#pragma unroll
    for (int gate = 0; gate < 3; ++gate)
      wf[kk * 3 + gate] =
          *(const short8*)&Whh[(long)((gate << 9) + d) * 512 + kk * 32 + lk * 8];

  const float bR = bhh[d], bZ = bhh[512 + d], bN = bhh[1024 + d];

  float hreg[4] = {0.f, 0.f, 0.f, 0.f};

  // per-lane A-frag base: row = g0+lc, k-offset lk*8
  const bf16* hA[2] = { h0 + (g0 + lc) * 512 + lk * 8,
                        h1 + (g0 + lc) * 512 + lk * 8 };
  long gibase[4], ysbase[4];
  int hsb[4];
#pragma unroll
  for (int j = 0; j < 4; ++j) {
    const int g = g0 + lk * 4 + j;
    gibase[j] = (long)g * 512 * 1536 + d;
    ysbase[j] = (long)g * 512 * 512 + d;
    hsb[j]    = g * 512 + d;
  }
  int* mycnt = cnt + chain * 512;

  for (int l = 0; l < 512; ++l) {
    // gi loads do not depend on h: issue before the flag wait to hide HBM latency
    float giv[12];
#pragma unroll
    for (int j = 0; j < 4; ++j) {
      giv[j * 3 + 0] = __bfloat162float(gi[gibase[j]]);
      giv[j * 3 + 1] = __bfloat162float(gi[gibase[j] + 512]);
      giv[j * 3 + 2] = __bfloat162float(gi[gibase[j] + 1024]);
      gibase[j] += 1536;
    }

    f32x4 acc[3] = { (f32x4){0.f,0.f,0.f,0.f}, (f32x4){0.f,0.f,0.f,0.f}, (f32x4){0.f,0.f,0.f,0.f} };
    if (l > 0) {
      int v;
      do {
        v = 0;
        if (lane == 0)
          v = __hip_atomic_load(&mycnt[l - 1], __ATOMIC_ACQUIRE, __HIP_MEMORY_SCOPE_AGENT);
        v = __shfl(v, 0);
        if (v < 32) __builtin_amdgcn_s_sleep(8);
      } while (v < 32);

      const bf16* ha = hA[(l & 1) ^ 1];      // H_{l-1} lives in buf[(l-1)&1]
#pragma unroll
      for (int kk = 0; kk < 16; ++kk) {
        const short8 af = *(const short8*)&ha[kk * 32];
#pragma unroll
        for (int gate = 0; gate < 3; ++gate)
          acc[gate] = __builtin_amdgcn_mfma_f32_16x16x32_bf16(af, wf[kk * 3 + gate], acc[gate], 0, 0, 0);
      }
    }

    bf16* hbw = (l & 1) ? h1 : h0;           // H_l goes to buf[l&1]
    bf16 hnb[4];
#pragma unroll
    for (int j = 0; j < 4; ++j) {
      const float r = 1.f / (1.f + __expf(-(giv[j * 3 + 0] + acc[0][j] + bR)));
      const float z = 1.f / (1.f + __expf(-(giv[j * 3 + 1] + acc[1][j] + bZ)));
      const float n = tanhf(giv[j * 3 + 2] + r * (acc[2][j] + bN));
      const float hn = (1.f - z) * n + z * hreg[j];
      hreg[j] = hn;
      hnb[j] = __float2bfloat16(hn);
      hbw[hsb[j]] = hnb[j];
    }
    // release: drains this wave's h stores (vmcnt is wave-wide) + L2 writeback
    if (lane == 0)
      __hip_atomic_fetch_add(&mycnt[l], 1, __ATOMIC_RELEASE, __HIP_MEMORY_SCOPE_AGENT);
    // ys is only consumed after kernel end; store after the release so its
    // HBM latency isn't on the sync critical path
#pragma unroll
    for (int j = 0; j < 4; ++j) {
      ys[ysbase[j]] = hnb[j];
      ysbase[j] += 512;
    }
  }
}

// ---------------- launch ----------------
extern "C" void kernel_launch(void* const* d_in, const int* in_sizes, int n_in,
                              void* d_out, int out_size, void* d_ws, size_t ws_size,
                              hipStream_t stream)
{
  (void)in_sizes; (void)n_in; (void)out_size; (void)ws_size;
  const float* in_feats = (const float*)d_in[0];
  const int*   e_src    = (const int*)d_in[1];
  const int*   e_dst    = (const int*)d_in[2];
  const int*   seq      = (const int*)d_in[3];
  const float* W_conv   = (const float*)d_in[4];
  const float* b_conv   = (const float*)d_in[5];
  const float* W_ff1    = (const float*)d_in[6];
  const float* b_ff1    = (const float*)d_in[7];
  const float* W_ih     = (const float*)d_in[8];
  const float* W_hh     = (const float*)d_in[9];
  const float* b_ih     = (const float*)d_in[10];
  const float* b_hh     = (const float*)d_in[11];
  const float* W_ff2    = (const float*)d_in[12];
  const float* b_ff2    = (const float*)d_in[13];
  (void)b_ih;

  uint8_t* ws = (uint8_t*)d_ws;
  int*  deg     = (int*) (ws + 0);
  int*  cursor  = (int*) (ws + 262144u);
  int*  roff    = (int*) (ws + 524288u);
  bf16* WcT     = (bf16*)(ws + 1048576u);
  bf16* Wf1T    = (bf16*)(ws + 1572864u);
  bf16* Wf2T    = (bf16*)(ws + 2097152u);
  bf16* WihB    = (bf16*)(ws + 2621440u);
  bf16* WhhB    = (bf16*)(ws + 4194304u);
  bf16* hbf0    = (bf16*)(ws + 5767168u);
  bf16* hbf1    = (bf16*)(ws + 5898240u);
  int*  csr     = (int*) (ws + 6291456u);
  int*  cnt     = (int*) (ws + 10485760u);   // 8*512 ints
  int*  partial = (int*) (ws + 10616832u);   // 64 ints
  int*  sbase   = (int*) (ws + 10620928u);   // 65 ints
  bf16* med2    = (bf16*)(ws + 16777216u);   // 67MB; reused as ys after gi GEMM
  bf16* ysb     = med2;
  bf16* gib     = (bf16*)(ws + 83886080u);   // 192MB; agg/med1 live here pre-gi
  bf16* aggb    = (bf16*)(ws + 83886080u);
  bf16* med1    = (bf16*)(ws + 150994944u);

  hipMemsetAsync(deg, 0, NN * 4, stream);
  hipMemsetAsync(cnt, 0, 8 * 512 * 4, stream);

  k_prep <<<3072, 256, 0, stream>>>(W_conv, W_ff1, W_ff2, W_ih, W_hh, WcT, Wf1T, Wf2T, WihB, WhhB);
  k_deg  <<<EE / 256, 256, 0, stream>>>(e_dst, deg);
  k_scan1<<<64, 1024, 0, stream>>>(deg, roff, partial);
  k_scan2<<<1, 64, 0, stream>>>(partial, sbase);
  k_scan3<<<64, 1024, 0, stream>>>(sbase, roff, cursor);
  k_fill <<<EE / 256, 256, 0, stream>>>(e_src, e_dst, cursor, csr);
  k_agg  <<<NN, 128, 0, stream>>>(in_feats, csr, roff, aggb);

  dim3 g512(4, 512), g1536(12, 512);
  k_gemm<false, false, false><<<g512,  256, 0, stream>>>(aggb, WcT,  b_conv, nullptr, med1, nullptr, 512);
  k_gemm<false, true,  false><<<g512,  256, 0, stream>>>(med1, Wf1T, b_ff1,  nullptr, med2, nullptr, 512);
  k_gemm<true,  false, false><<<g1536, 256, 0, stream>>>(med2, WihB, b_ih,   seq,     gib,  nullptr, 1536);

  k_gru_persist<<<64, 256, 0, stream>>>(WhhB, b_hh, gib, hbf0, hbf1, ysb, cnt);

  k_gemm<false, false, true><<<g512, 256, 0, stream>>>(ysb, Wf2T, b_ff2, seq, nullptr, (float*)d_out, 512);
}

// Round 3
// 5897.907 us; speedup vs baseline: 1.4082x; 1.4082x over previous
//
#include <hip/hip_runtime.h>
#include <hip/hip_bf16.h>
#include <stdint.h>

typedef __hip_bfloat16 bf16;
typedef __attribute__((ext_vector_type(8))) short short8;
typedef __attribute__((ext_vector_type(4))) float f32x4;

#define NN 65536
#define DD 512
#define EE 1048576
#define GG 128
#define LL 512

static __device__ __forceinline__ void gld_lds16(const void* g, void* l) {
  __builtin_amdgcn_global_load_lds((const __attribute__((address_space(1))) uint32_t*)g,
                                   (__attribute__((address_space(3))) uint32_t*)l, 16, 0, 0);
}

// ---------------- prep: transpose/cast weights to bf16 ----------------
__global__ __launch_bounds__(256) void k_prep(
    const float* __restrict__ Wc, const float* __restrict__ Wf1, const float* __restrict__ Wf2,
    const float* __restrict__ Wih, const float* __restrict__ Whh,
    bf16* __restrict__ WcT, bf16* __restrict__ Wf1T, bf16* __restrict__ Wf2T,
    bf16* __restrict__ WihB, bf16* __restrict__ WhhB)
{
  const int i = blockIdx.x * 256 + threadIdx.x;
  if (i < 512 * 512) {
    const int k = i >> 9, n = i & 511;
    WcT [n * 512 + k] = __float2bfloat16(Wc [i]);
    Wf1T[n * 512 + k] = __float2bfloat16(Wf1[i]);
    Wf2T[n * 512 + k] = __float2bfloat16(Wf2[i]);
  }
  if (i < 1536 * 512) {
    WihB[i] = __float2bfloat16(Wih[i]);
    WhhB[i] = __float2bfloat16(Whh[i]);
  }
}

// ---------------- cast node features to bf16 (halves gather volume) ----------------
__global__ __launch_bounds__(256) void k_cast(const float* __restrict__ f, bf16* __restrict__ o) {
  const long i = (long)(blockIdx.x * 256 + threadIdx.x) * 4;
  const float4 v = *(const float4*)&f[i];
  union { bf16 b[4]; ushort4 u; } pk;
  pk.b[0] = __float2bfloat16(v.x);
  pk.b[1] = __float2bfloat16(v.y);
  pk.b[2] = __float2bfloat16(v.z);
  pk.b[3] = __float2bfloat16(v.w);
  *(ushort4*)&o[i] = pk.u;
}

// ---------------- CSR build ----------------
__global__ __launch_bounds__(256) void k_deg(const int* __restrict__ dst, int* __restrict__ deg) {
  const int e = blockIdx.x * 256 + threadIdx.x;
  atomicAdd(&deg[dst[e]], 1);
}

// parallel 3-phase exclusive scan of deg[65536]
__global__ __launch_bounds__(1024) void k_scan1(const int* __restrict__ deg,
                                                int* __restrict__ roff, int* __restrict__ partial) {
  __shared__ int sd[1024];
  const int t = threadIdx.x, b = blockIdx.x, i = b * 1024 + t;
  const int v = deg[i];
  sd[t] = v;
  __syncthreads();
  for (int off = 1; off < 1024; off <<= 1) {
    int add = (t >= off) ? sd[t - off] : 0;
    __syncthreads();
    sd[t] += add;
    __syncthreads();
  }
  roff[i] = sd[t] - v;          // exclusive within chunk
  if (t == 1023) partial[b] = sd[t];
}

__global__ __launch_bounds__(64) void k_scan2(const int* __restrict__ partial, int* __restrict__ base) {
  __shared__ int sd[64];
  const int t = threadIdx.x;
  const int v = partial[t];
  sd[t] = v;
  __syncthreads();
  for (int off = 1; off < 64; off <<= 1) {
    int add = (t >= off) ? sd[t - off] : 0;
    __syncthreads();
    sd[t] += add;
    __syncthreads();
  }
  base[t] = sd[t] - v;
  if (t == 63) base[64] = sd[63];
}

__global__ __launch_bounds__(1024) void k_scan3(const int* __restrict__ base,
                                                int* __restrict__ roff, int* __restrict__ cursor) {
  const int b = blockIdx.x, t = threadIdx.x, i = b * 1024 + t;
  const int v = roff[i] + base[b];
  roff[i] = v;
  cursor[i] = v;
  if (i == 0) roff[NN] = base[64];
}

__global__ __launch_bounds__(256) void k_fill(const int* __restrict__ src, const int* __restrict__ dst,
                                              int* __restrict__ cursor, int* __restrict__ csr) {
  const int e = blockIdx.x * 256 + threadIdx.x;
  const int p = atomicAdd(&cursor[dst[e]], 1);
  csr[p] = src[e];
}

// ---------------- mean aggregation (bf16 gather, fp32 accum) ----------------
__global__ __launch_bounds__(128) void k_agg(
    const bf16* __restrict__ featsb, const int* __restrict__ csr,
    const int* __restrict__ roff, bf16* __restrict__ agg)
{
  const int n = blockIdx.x, t = threadIdx.x;
  const int s0 = roff[n], s1 = roff[n + 1];
  float a0 = 0.f, a1 = 0.f, a2 = 0.f, a3 = 0.f;
  for (int i = s0; i < s1; ++i) {
    const int s = csr[i];
    const ushort4 v = *(const ushort4*)&featsb[(long)s * 512 + t * 4];
    bf16 b0, b1, b2, b3;
    *(uint16_t*)&b0 = v.x; *(uint16_t*)&b1 = v.y;
    *(uint16_t*)&b2 = v.z; *(uint16_t*)&b3 = v.w;
    a0 += __bfloat162float(b0); a1 += __bfloat162float(b1);
    a2 += __bfloat162float(b2); a3 += __bfloat162float(b3);
  }
  const float sc = 1.f / fmaxf((float)(s1 - s0), 1.f);
  union { bf16 b[4]; ushort4 u; } pk;
  pk.b[0] = __float2bfloat16(a0 * sc);
  pk.b[1] = __float2bfloat16(a1 * sc);
  pk.b[2] = __float2bfloat16(a2 * sc);
  pk.b[3] = __float2bfloat16(a3 * sc);
  *(ushort4*)&agg[(long)n * 512 + t * 4] = pk.u;
}

// ---------------- bf16 GEMM: C[M,Ncols] = A[M,512] @ Bt[Ncols,512]^T + bias ----------------
template<bool GATHER, bool RELU, bool SCATTER>
__global__ __launch_bounds__(256) void k_gemm(
    const bf16* __restrict__ A, const bf16* __restrict__ Bt,
    const float* __restrict__ bias, const int* __restrict__ gidx,
    bf16* __restrict__ outb, float* __restrict__ outf, int Ncols)
{
  __shared__ bf16 lsA[128 * 64];
  __shared__ bf16 lsB[128 * 64];
  const int t = threadIdx.x;
  const int lane = t & 63, wid = t >> 6;
  const int wr = wid >> 1, wc = wid & 1;
  const int tm = blockIdx.y * 128, tn = blockIdx.x * 128;
  const int col8 = (t & 7) * 8;
  const int rsub = t >> 3;
  const int lc = lane & 15, lk = lane >> 4;

  long arow[4], brow[4];
#pragma unroll
  for (int i = 0; i < 4; ++i) {
    const int r = tm + i * 32 + rsub;
    int ar = r;
    if constexpr (GATHER) ar = gidx[r];
    arow[i] = (long)ar * 512;
    brow[i] = (long)(tn + i * 32 + rsub) * 512;
  }

  f32x4 acc[4][4];
#pragma unroll
  for (int a = 0; a < 4; ++a)
#pragma unroll
    for (int b = 0; b < 4; ++b) acc[a][b] = (f32x4){0.f, 0.f, 0.f, 0.f};

  for (int ks = 0; ks < 8; ++ks) {
    const int k0 = ks * 64;
#pragma unroll
    for (int i = 0; i < 4; ++i) {
      gld_lds16(A  + arow[i] + k0 + col8, &lsA[i * 2048 + t * 8]);
      gld_lds16(Bt + brow[i] + k0 + col8, &lsB[i * 2048 + t * 8]);
    }
    __syncthreads();
#pragma unroll
    for (int kk = 0; kk < 2; ++kk) {
      short8 af[4], bfr[4];
#pragma unroll
      for (int mi = 0; mi < 4; ++mi)
        af[mi] = *(const short8*)&lsA[(wr * 64 + mi * 16 + lc) * 64 + kk * 32 + lk * 8];
#pragma unroll
      for (int ni = 0; ni < 4; ++ni)
        bfr[ni] = *(const short8*)&lsB[(wc * 64 + ni * 16 + lc) * 64 + kk * 32 + lk * 8];
#pragma unroll
      for (int mi = 0; mi < 4; ++mi)
#pragma unroll
        for (int ni = 0; ni < 4; ++ni)
          acc[mi][ni] = __builtin_amdgcn_mfma_f32_16x16x32_bf16(af[mi], bfr[ni], acc[mi][ni], 0, 0, 0);
    }
    __syncthreads();
  }

  float bv[4];
#pragma unroll
  for (int ni = 0; ni < 4; ++ni) bv[ni] = bias[tn + wc * 64 + ni * 16 + lc];

#pragma unroll
  for (int mi = 0; mi < 4; ++mi) {
    const int r0 = tm + wr * 64 + mi * 16 + lk * 4;
#pragma unroll
    for (int j = 0; j < 4; ++j) {
      const int row = r0 + j;
      long orow;
      if constexpr (SCATTER) orow = (long)gidx[row] * 512;
      else                   orow = (long)row * Ncols;
#pragma unroll
      for (int ni = 0; ni < 4; ++ni) {
        float v = acc[mi][ni][j] + bv[ni];
        if constexpr (RELU) v = fmaxf(v, 0.f);
        const int c = tn + wc * 64 + ni * 16 + lc;
        if constexpr (SCATTER) outf[orow + c] = v;
        else                   outb[orow + c] = __float2bfloat16(v);
      }
    }
  }
}

// ---------------- persistent GRU, fence-free sc1 protocol ----------------
// 64 blocks = 2 jm x 32 jc. 4 waves/block; wave w handles chain jm*4+w
// (16 groups) x 16 d-cols. W_hh slice (48x512) in LDS (shared by the 4 waves).
// Sync: per-(chain,jc) MONOTONIC stamp flag. Producer: h stores via
// global_store_short sc0 sc1 (write-through to coherent point), s_waitcnt
// vmcnt(0), then relaxed-agent 4B flag store (sc1). Consumer: poll 32 flags
// in one relaxed-agent load (lane&31 each, no invalidates), then read h via
// relaxed-agent dword loads (sc1 -> coherent point, stale L2 bypassed).
// No RMW, no acquire/release fences, no buffer_inv/wbl2 anywhere.
__global__ __launch_bounds__(256, 2) void k_gru2(
    const bf16* __restrict__ Whh, const float* __restrict__ bhh,
    const bf16* __restrict__ gi, bf16* __restrict__ h0, bf16* __restrict__ h1,
    bf16* __restrict__ ys, int* __restrict__ flags)
{
  __shared__ bf16 lsW[48 * 520];
  const int t = threadIdx.x, lane = t & 63, w = t >> 6;
  const int jm = blockIdx.x >> 5, jc = blockIdx.x & 31;
  const int lc = lane & 15, lk = lane >> 4;
  const int chain = jm * 4 + w;        // 0..7
  const int g0 = chain * 16;           // this wave's 16 groups
  const int d = jc * 16 + lc;          // this lane's output column

  // stage Whh slice: rows 0..15 -> gate r, 16..31 -> z, 32..47 -> n (cols jc*16..+16)
#pragma unroll
  for (int it = 0; it < 12; ++it) {
    const int c = it * 256 + t;
    const int row = c >> 6, col = (c & 63) * 8;
    const int e = (row < 16) ? (jc * 16 + row)
                : (row < 32) ? (512 + jc * 16 + row - 16)
                             : (1024 + jc * 16 + row - 32);
    *(uint4*)&lsW[row * 520 + col] = *(const uint4*)&Whh[(long)e * 512 + col];
  }
  __syncthreads();

  const float bR = bhh[d], bZ = bhh[512 + d], bN = bhh[1024 + d];
  float hreg[4] = {0.f, 0.f, 0.f, 0.f};

  // per-lane A-frag dword base: row g0+lc, k-offset lk*8 bf16 (= 4 dwords)
  const uint32_t* hAd[2] = { (const uint32_t*)(h0 + (g0 + lc) * 512 + lk * 8),
                             (const uint32_t*)(h1 + (g0 + lc) * 512 + lk * 8) };
  long gibase[4], ysbase[4];
  int hsb[4];
#pragma unroll
  for (int j = 0; j < 4; ++j) {
    const int g = g0 + lk * 4 + j;
    gibase[j] = (long)g * 512 * 1536 + d;
    ysbase[j] = (long)g * 512 * 512 + d;
    hsb[j]    = g * 512 + d;
  }
  int* myflags = flags + chain * 32;
  int* myflag  = flags + chain * 32 + jc;

  for (int l = 0; l < 512; ++l) {
    // gi loads don't depend on h: issue before the flag wait (plain cached)
    float giv[12];
#pragma unroll
    for (int j = 0; j < 4; ++j) {
      giv[j * 3 + 0] = __bfloat162float(gi[gibase[j]]);
      giv[j * 3 + 1] = __bfloat162float(gi[gibase[j] + 512]);
      giv[j * 3 + 2] = __bfloat162float(gi[gibase[j] + 1024]);
      gibase[j] += 1536;
    }

    f32x4 acc[3] = { (f32x4){0.f,0.f,0.f,0.f}, (f32x4){0.f,0.f,0.f,0.f}, (f32x4){0.f,0.f,0.f,0.f} };
    if (l > 0) {
      // wait for all 32 producers of this chain to have stamped step l
      int ok;
      do {
        const int v = __hip_atomic_load(&myflags[lane & 31], __ATOMIC_RELAXED,
                                        __HIP_MEMORY_SCOPE_AGENT);
        ok = __all(v >= l);
        if (!ok) __builtin_amdgcn_s_sleep(1);
      } while (!ok);
      asm volatile("" ::: "memory");  // keep h loads below the poll

      const uint32_t* ha = hAd[(l & 1) ^ 1];   // H_{l-1} lives in buf[(l-1)&1]
      short8 af[16];
#pragma unroll
      for (int kk = 0; kk < 16; ++kk) {
        union { uint32_t u[4]; short8 s; } cv;
#pragma unroll
        for (int q = 0; q < 4; ++q)
          cv.u[q] = __hip_atomic_load(ha + kk * 16 + q, __ATOMIC_RELAXED,
                                      __HIP_MEMORY_SCOPE_AGENT);
        af[kk] = cv.s;
      }
#pragma unroll
      for (int kk = 0; kk < 16; ++kk)
#pragma unroll
        for (int gate = 0; gate < 3; ++gate) {
          const short8 bfr = *(const short8*)&lsW[(gate * 16 + lc) * 520 + kk * 32 + lk * 8];
          acc[gate] = __builtin_amdgcn_mfma_f32_16x16x32_bf16(af[kk], bfr, acc[gate], 0, 0, 0);
        }
    }

    bf16* hbw = (l & 1) ? h1 : h0;             // H_l goes to buf[l&1]
    bf16 hnb[4];
#pragma unroll
    for (int j = 0; j < 4; ++j) {
      const float r = 1.f / (1.f + __expf(-(giv[j * 3 + 0] + acc[0][j] + bR)));
      const float z = 1.f / (1.f + __expf(-(giv[j * 3 + 1] + acc[1][j] + bZ)));
      const float n = tanhf(giv[j * 3 + 2] + r * (acc[2][j] + bN));
      const float hn = (1.f - z) * n + z * hreg[j];
      hreg[j] = hn;
      hnb[j] = __float2bfloat16(hn);
      uint32_t bits = *(const uint16_t*)&hnb[j];
      const bf16* p = hbw + hsb[j];
      asm volatile("global_store_short %0, %1, off sc0 sc1"
                   :: "v"(p), "v"(bits) : "memory");
    }
    // drain this wave's h stores to the coherent point, then stamp
    asm volatile("s_waitcnt vmcnt(0)" ::: "memory");
    if (lane == 0)
      __hip_atomic_store(myflag, l + 1, __ATOMIC_RELAXED, __HIP_MEMORY_SCOPE_AGENT);
    // ys only consumed after kernel end; off the sync critical path
#pragma unroll
    for (int j = 0; j < 4; ++j) {
      ys[ysbase[j]] = hnb[j];
      ysbase[j] += 512;
    }
  }
}

// ---------------- launch ----------------
extern "C" void kernel_launch(void* const* d_in, const int* in_sizes, int n_in,
                              void* d_out, int out_size, void* d_ws, size_t ws_size,
                              hipStream_t stream)
{
  (void)in_sizes; (void)n_in; (void)out_size; (void)ws_size;
  const float* in_feats = (const float*)d_in[0];
  const int*   e_src    = (const int*)d_in[1];
  const int*   e_dst    = (const int*)d_in[2];
  const int*   seq      = (const int*)d_in[3];
  const float* W_conv   = (const float*)d_in[4];
  const float* b_conv   = (const float*)d_in[5];
  const float* W_ff1    = (const float*)d_in[6];
  const float* b_ff1    = (const float*)d_in[7];
  const float* W_ih     = (const float*)d_in[8];
  const float* W_hh     = (const float*)d_in[9];
  const float* b_ih     = (const float*)d_in[10];
  const float* b_hh     = (const float*)d_in[11];
  const float* W_ff2    = (const float*)d_in[12];
  const float* b_ff2    = (const float*)d_in[13];

  uint8_t* ws = (uint8_t*)d_ws;
  int*  deg     = (int*) (ws + 0);
  int*  cursor  = (int*) (ws + 262144u);
  int*  roff    = (int*) (ws + 524288u);
  bf16* WcT     = (bf16*)(ws + 1048576u);
  bf16* Wf1T    = (bf16*)(ws + 1572864u);
  bf16* Wf2T    = (bf16*)(ws + 2097152u);
  bf16* WihB    = (bf16*)(ws + 2621440u);
  bf16* WhhB    = (bf16*)(ws + 4194304u);
  bf16* hbf0    = (bf16*)(ws + 5767168u);
  bf16* hbf1    = (bf16*)(ws + 5898240u);
  int*  csr     = (int*) (ws + 6291456u);
  int*  flags   = (int*) (ws + 10485760u);   // 8*32 ints (monotonic stamps)
  int*  partial = (int*) (ws + 10616832u);   // 64 ints
  int*  sbase   = (int*) (ws + 10620928u);   // 65 ints
  bf16* med2    = (bf16*)(ws + 16777216u);   // 67MB; reused as ys after gi GEMM
  bf16* ysb     = med2;
  bf16* gib     = (bf16*)(ws + 83886080u);   // 201MB; aggb/med1/featsb live here pre-gi
  bf16* aggb    = (bf16*)(ws + 83886080u);
  bf16* med1    = (bf16*)(ws + 150994944u);  // also featsb (dead before med1 written)
  bf16* featsb  = (bf16*)(ws + 150994944u);

  hipMemsetAsync(deg,   0, NN * 4,     stream);
  hipMemsetAsync(flags, 0, 8 * 32 * 4, stream);
  (void)hbf0; (void)hbf1;

  k_prep <<<3072, 256, 0, stream>>>(W_conv, W_ff1, W_ff2, W_ih, W_hh, WcT, Wf1T, Wf2T, WihB, WhhB);
  k_cast <<<NN * DD / 1024, 256, 0, stream>>>(in_feats, featsb);
  k_deg  <<<EE / 256, 256, 0, stream>>>(e_dst, deg);
  k_scan1<<<64, 1024, 0, stream>>>(deg, roff, partial);
  k_scan2<<<1, 64, 0, stream>>>(partial, sbase);
  k_scan3<<<64, 1024, 0, stream>>>(sbase, roff, cursor);
  k_fill <<<EE / 256, 256, 0, stream>>>(e_src, e_dst, cursor, csr);
  k_agg  <<<NN, 128, 0, stream>>>(featsb, csr, roff, aggb);

  dim3 g512(4, 512), g1536(12, 512);
  k_gemm<false, false, false><<<g512,  256, 0, stream>>>(aggb, WcT,  b_conv, nullptr, med1, nullptr, 512);
  k_gemm<false, true,  false><<<g512,  256, 0, stream>>>(med1, Wf1T, b_ff1,  nullptr, med2, nullptr, 512);
  k_gemm<true,  false, false><<<g1536, 256, 0, stream>>>(med2, WihB, b_ih,   seq,     gib,  nullptr, 1536);

  // h0/h1 double buffers (bf16, 128x512 each) — l=0 skips reads, no init needed
  bf16* h0 = (bf16*)(ws + 11534336u);
  bf16* h1 = (bf16*)(ws + 11665408u);
  k_gru2<<<64, 256, 0, stream>>>(WhhB, b_hh, gib, h0, h1, ysb, flags);

  k_gemm<false, false, true><<<g512, 256, 0, stream>>>(ysb, Wf2T, b_ff2, seq, nullptr, (float*)d_out, 512);
}

// Round 4
// 3310.403 us; speedup vs baseline: 2.5089x; 1.7816x over previous
//
#include <hip/hip_runtime.h>
#include <hip/hip_bf16.h>
#include <stdint.h>

typedef __hip_bfloat16 bf16;
typedef __attribute__((ext_vector_type(8))) short short8;
typedef __attribute__((ext_vector_type(4))) float f32x4;
typedef __attribute__((ext_vector_type(4))) unsigned int u32x4;

#define NN 65536
#define DD 512
#define EE 1048576
#define GG 128
#define LL 512

static __device__ __forceinline__ void gld_lds16(const void* g, void* l) {
  __builtin_amdgcn_global_load_lds((const __attribute__((address_space(1))) uint32_t*)g,
                                   (__attribute__((address_space(3))) uint32_t*)l, 16, 0, 0);
}

// ---------------- prep: transpose/cast weights to bf16 ----------------
__global__ __launch_bounds__(256) void k_prep(
    const float* __restrict__ Wc, const float* __restrict__ Wf1, const float* __restrict__ Wf2,
    const float* __restrict__ Wih, const float* __restrict__ Whh,
    bf16* __restrict__ WcT, bf16* __restrict__ Wf1T, bf16* __restrict__ Wf2T,
    bf16* __restrict__ WihB, bf16* __restrict__ WhhB)
{
  const int i = blockIdx.x * 256 + threadIdx.x;
  if (i < 512 * 512) {
    const int k = i >> 9, n = i & 511;
    WcT [n * 512 + k] = __float2bfloat16(Wc [i]);
    Wf1T[n * 512 + k] = __float2bfloat16(Wf1[i]);
    Wf2T[n * 512 + k] = __float2bfloat16(Wf2[i]);
  }
  if (i < 1536 * 512) {
    WihB[i] = __float2bfloat16(Wih[i]);
    WhhB[i] = __float2bfloat16(Whh[i]);
  }
}

// ---------------- cast node features to bf16 (halves gather volume) ----------------
__global__ __launch_bounds__(256) void k_cast(const float* __restrict__ f, bf16* __restrict__ o) {
  const long i = (long)(blockIdx.x * 256 + threadIdx.x) * 4;
  const float4 v = *(const float4*)&f[i];
  union { bf16 b[4]; ushort4 u; } pk;
  pk.b[0] = __float2bfloat16(v.x);
  pk.b[1] = __float2bfloat16(v.y);
  pk.b[2] = __float2bfloat16(v.z);
  pk.b[3] = __float2bfloat16(v.w);
  *(ushort4*)&o[i] = pk.u;
}

// ---------------- CSR build ----------------
__global__ __launch_bounds__(256) void k_deg(const int* __restrict__ dst, int* __restrict__ deg) {
  const int e = blockIdx.x * 256 + threadIdx.x;
  atomicAdd(&deg[dst[e]], 1);
}

// parallel 3-phase exclusive scan of deg[65536]
__global__ __launch_bounds__(1024) void k_scan1(const int* __restrict__ deg,
                                                int* __restrict__ roff, int* __restrict__ partial) {
  __shared__ int sd[1024];
  const int t = threadIdx.x, b = blockIdx.x, i = b * 1024 + t;
  const int v = deg[i];
  sd[t] = v;
  __syncthreads();
  for (int off = 1; off < 1024; off <<= 1) {
    int add = (t >= off) ? sd[t - off] : 0;
    __syncthreads();
    sd[t] += add;
    __syncthreads();
  }
  roff[i] = sd[t] - v;          // exclusive within chunk
  if (t == 1023) partial[b] = sd[t];
}

__global__ __launch_bounds__(64) void k_scan2(const int* __restrict__ partial, int* __restrict__ base) {
  __shared__ int sd[64];
  const int t = threadIdx.x;
  const int v = partial[t];
  sd[t] = v;
  __syncthreads();
  for (int off = 1; off < 64; off <<= 1) {
    int add = (t >= off) ? sd[t - off] : 0;
    __syncthreads();
    sd[t] += add;
    __syncthreads();
  }
  base[t] = sd[t] - v;
  if (t == 63) base[64] = sd[63];
}

__global__ __launch_bounds__(1024) void k_scan3(const int* __restrict__ base,
                                                int* __restrict__ roff, int* __restrict__ cursor) {
  const int b = blockIdx.x, t = threadIdx.x, i = b * 1024 + t;
  const int v = roff[i] + base[b];
  roff[i] = v;
  cursor[i] = v;
  if (i == 0) roff[NN] = base[64];
}

__global__ __launch_bounds__(256) void k_fill(const int* __restrict__ src, const int* __restrict__ dst,
                                              int* __restrict__ cursor, int* __restrict__ csr) {
  const int e = blockIdx.x * 256 + threadIdx.x;
  const int p = atomicAdd(&cursor[dst[e]], 1);
  csr[p] = src[e];
}

// ---------------- mean aggregation (bf16 gather, fp32 accum) ----------------
__global__ __launch_bounds__(128) void k_agg(
    const bf16* __restrict__ featsb, const int* __restrict__ csr,
    const int* __restrict__ roff, bf16* __restrict__ agg)
{
  const int n = blockIdx.x, t = threadIdx.x;
  const int s0 = roff[n], s1 = roff[n + 1];
  float a0 = 0.f, a1 = 0.f, a2 = 0.f, a3 = 0.f;
  for (int i = s0; i < s1; ++i) {
    const int s = csr[i];
    const ushort4 v = *(const ushort4*)&featsb[(long)s * 512 + t * 4];
    bf16 b0, b1, b2, b3;
    *(uint16_t*)&b0 = v.x; *(uint16_t*)&b1 = v.y;
    *(uint16_t*)&b2 = v.z; *(uint16_t*)&b3 = v.w;
    a0 += __bfloat162float(b0); a1 += __bfloat162float(b1);
    a2 += __bfloat162float(b2); a3 += __bfloat162float(b3);
  }
  const float sc = 1.f / fmaxf((float)(s1 - s0), 1.f);
  union { bf16 b[4]; ushort4 u; } pk;
  pk.b[0] = __float2bfloat16(a0 * sc);
  pk.b[1] = __float2bfloat16(a1 * sc);
  pk.b[2] = __float2bfloat16(a2 * sc);
  pk.b[3] = __float2bfloat16(a3 * sc);
  *(ushort4*)&agg[(long)n * 512 + t * 4] = pk.u;
}

// ---------------- bf16 GEMM: C[M,Ncols] = A[M,512] @ Bt[Ncols,512]^T + bias ----------------
template<bool GATHER, bool RELU, bool SCATTER>
__global__ __launch_bounds__(256) void k_gemm(
    const bf16* __restrict__ A, const bf16* __restrict__ Bt,
    const float* __restrict__ bias, const int* __restrict__ gidx,
    bf16* __restrict__ outb, float* __restrict__ outf, int Ncols)
{
  __shared__ bf16 lsA[128 * 64];
  __shared__ bf16 lsB[128 * 64];
  const int t = threadIdx.x;
  const int lane = t & 63, wid = t >> 6;
  const int wr = wid >> 1, wc = wid & 1;
  const int tm = blockIdx.y * 128, tn = blockIdx.x * 128;
  const int col8 = (t & 7) * 8;
  const int rsub = t >> 3;
  const int lc = lane & 15, lk = lane >> 4;

  long arow[4], brow[4];
#pragma unroll
  for (int i = 0; i < 4; ++i) {
    const int r = tm + i * 32 + rsub;
    int ar = r;
    if constexpr (GATHER) ar = gidx[r];
    arow[i] = (long)ar * 512;
    brow[i] = (long)(tn + i * 32 + rsub) * 512;
  }

  f32x4 acc[4][4];
#pragma unroll
  for (int a = 0; a < 4; ++a)
#pragma unroll
    for (int b = 0; b < 4; ++b) acc[a][b] = (f32x4){0.f, 0.f, 0.f, 0.f};

  for (int ks = 0; ks < 8; ++ks) {
    const int k0 = ks * 64;
#pragma unroll
    for (int i = 0; i < 4; ++i) {
      gld_lds16(A  + arow[i] + k0 + col8, &lsA[i * 2048 + t * 8]);
      gld_lds16(Bt + brow[i] + k0 + col8, &lsB[i * 2048 + t * 8]);
    }
    __syncthreads();
#pragma unroll
    for (int kk = 0; kk < 2; ++kk) {
      short8 af[4], bfr[4];
#pragma unroll
      for (int mi = 0; mi < 4; ++mi)
        af[mi] = *(const short8*)&lsA[(wr * 64 + mi * 16 + lc) * 64 + kk * 32 + lk * 8];
#pragma unroll
      for (int ni = 0; ni < 4; ++ni)
        bfr[ni] = *(const short8*)&lsB[(wc * 64 + ni * 16 + lc) * 64 + kk * 32 + lk * 8];
#pragma unroll
      for (int mi = 0; mi < 4; ++mi)
#pragma unroll
        for (int ni = 0; ni < 4; ++ni)
          acc[mi][ni] = __builtin_amdgcn_mfma_f32_16x16x32_bf16(af[mi], bfr[ni], acc[mi][ni], 0, 0, 0);
    }
    __syncthreads();
  }

  float bv[4];
#pragma unroll
  for (int ni = 0; ni < 4; ++ni) bv[ni] = bias[tn + wc * 64 + ni * 16 + lc];

#pragma unroll
  for (int mi = 0; mi < 4; ++mi) {
    const int r0 = tm + wr * 64 + mi * 16 + lk * 4;
#pragma unroll
    for (int j = 0; j < 4; ++j) {
      const int row = r0 + j;
      long orow;
      if constexpr (SCATTER) orow = (long)gidx[row] * 512;
      else                   orow = (long)row * Ncols;
#pragma unroll
      for (int ni = 0; ni < 4; ++ni) {
        float v = acc[mi][ni][j] + bv[ni];
        if constexpr (RELU) v = fmaxf(v, 0.f);
        const int c = tn + wc * 64 + ni * 16 + lc;
        if constexpr (SCATTER) outf[orow + c] = v;
        else                   outb[orow + c] = __float2bfloat16(v);
      }
    }
  }
}

// ---------------- persistent GRU v3 ----------------
// 64 blocks = 2 jm x 32 jc; 4 waves/block; wave w = chain jm*4+w (16 groups)
// x 16 d-cols (jc). W_hh slice in LDS. ys[g][l][d] doubles as the h state
// (write-once addresses). Producer: 4 short stores (sc0 sc1 write-through),
// s_waitcnt vmcnt(0), relaxed-agent flag stamp. Consumer: poll 32 flags
// (one lane each), then 16 batched global_load_dwordx4 sc0 sc1 off one base
// with immediate offsets -> ~1 pipelined L3 RTT instead of 16 serial ones
// (round-3 bug: VGPR=76 showed the compiler serialized 64 scalar atomic
// loads into 16 dependent RTTs).
__global__ __launch_bounds__(256, 1) void k_gru3(
    const bf16* __restrict__ Whh, const float* __restrict__ bhh,
    const bf16* __restrict__ gi, bf16* __restrict__ ys, int* __restrict__ flags)
{
  __shared__ bf16 lsW[48 * 520];
  const int t = threadIdx.x, lane = t & 63, w = t >> 6;
  const int jm = blockIdx.x >> 5, jc = blockIdx.x & 31;
  const int lc = lane & 15, lk = lane >> 4;
  const int chain = jm * 4 + w;        // 0..7
  const int g0 = chain * 16;           // this wave's 16 groups
  const int d = jc * 16 + lc;          // this lane's output column

  // stage Whh slice: rows 0..15 -> gate r, 16..31 -> z, 32..47 -> n (cols jc*16..+16)
#pragma unroll
  for (int it = 0; it < 12; ++it) {
    const int c = it * 256 + t;
    const int row = c >> 6, col = (c & 63) * 8;
    const int e = (row < 16) ? (jc * 16 + row)
                : (row < 32) ? (512 + jc * 16 + row - 16)
                             : (1024 + jc * 16 + row - 32);
    *(uint4*)&lsW[row * 520 + col] = *(const uint4*)&Whh[(long)e * 512 + col];
  }
  __syncthreads();

  const float bR = bhh[d], bZ = bhh[512 + d], bN = bhh[1024 + d];
  float hreg[4] = {0.f, 0.f, 0.f, 0.f};

  // consumer A-frag base: row g0+lc of ys[g][l][d] (l added per step), k-off lk*8
  const bf16* pa0 = ys + ((long)(g0 + lc) << 18) + lk * 8;
  long gibase[4], ysb4[4];
#pragma unroll
  for (int j = 0; j < 4; ++j) {
    const int g = g0 + lk * 4 + j;
    gibase[j] = (long)g * 786432 + d;        // g*512*1536
    ysb4[j]   = ((long)g << 18) + d;         // g*512*512
  }
  int* myflags = flags + chain * 32;
  int* myflag  = myflags + jc;

  for (int l = 0; l < 512; ++l) {
    // gi loads don't depend on h: issue before the flag wait (plain cached)
    float giv[12];
#pragma unroll
    for (int j = 0; j < 4; ++j) {
      giv[j * 3 + 0] = __bfloat162float(gi[gibase[j]]);
      giv[j * 3 + 1] = __bfloat162float(gi[gibase[j] + 512]);
      giv[j * 3 + 2] = __bfloat162float(gi[gibase[j] + 1024]);
      gibase[j] += 1536;
    }

    f32x4 acc[3] = { (f32x4){0.f,0.f,0.f,0.f}, (f32x4){0.f,0.f,0.f,0.f}, (f32x4){0.f,0.f,0.f,0.f} };
    if (l > 0) {
      // wait for all 32 producers of this chain to have stamped step l
      int ok;
      do {
        const int v = __hip_atomic_load(&myflags[lane & 31], __ATOMIC_RELAXED,
                                        __HIP_MEMORY_SCOPE_AGENT);
        ok = __all(v >= l);
      } while (!ok);
      asm volatile("" ::: "memory");

      // h_{l-1} = ys[:, l-1, :]; 16 coherent dwordx4 loads, all in flight
      const bf16* pa = pa0 + ((long)(l - 1) << 9);
      u32x4 hv[16];
#pragma unroll
      for (int kk = 0; kk < 16; ++kk)
        asm volatile("global_load_dwordx4 %0, %1, off offset:%2 sc0 sc1"
                     : "=v"(hv[kk]) : "v"(pa), "n"(kk * 64) : "memory");
      asm volatile("s_waitcnt vmcnt(0)" ::: "memory");
      __builtin_amdgcn_sched_barrier(0);

#pragma unroll
      for (int kk = 0; kk < 16; ++kk) {
        union { u32x4 u; short8 s; } cv;
        cv.u = hv[kk];
#pragma unroll
        for (int gate = 0; gate < 3; ++gate) {
          const short8 bfr = *(const short8*)&lsW[(gate * 16 + lc) * 520 + kk * 32 + lk * 8];
          acc[gate] = __builtin_amdgcn_mfma_f32_16x16x32_bf16(cv.s, bfr, acc[gate], 0, 0, 0);
        }
      }
    }

#pragma unroll
    for (int j = 0; j < 4; ++j) {
      const float r = 1.f / (1.f + __expf(-(giv[j * 3 + 0] + acc[0][j] + bR)));
      const float z = 1.f / (1.f + __expf(-(giv[j * 3 + 1] + acc[1][j] + bZ)));
      const float x2 = giv[j * 3 + 2] + r * (acc[2][j] + bN);
      const float ex = __expf(2.f * x2);
      const float n = 1.f - 2.f / (ex + 1.f);          // tanh
      const float hn = (1.f - z) * n + z * hreg[j];
      hreg[j] = hn;
      bf16 hnb = __float2bfloat16(hn);
      uint32_t bits = *(const uint16_t*)&hnb;
      const bf16* p = ys + ysb4[j] + ((long)l << 9);
      asm volatile("global_store_short %0, %1, off sc0 sc1"
                   :: "v"(p), "v"(bits) : "memory");
    }
    // drain this wave's ys stores to the coherent point, then stamp
    asm volatile("s_waitcnt vmcnt(0)" ::: "memory");
    if (lane == 0)
      __hip_atomic_store(myflag, l + 1, __ATOMIC_RELAXED, __HIP_MEMORY_SCOPE_AGENT);
  }
}

// ---------------- launch ----------------
extern "C" void kernel_launch(void* const* d_in, const int* in_sizes, int n_in,
                              void* d_out, int out_size, void* d_ws, size_t ws_size,
                              hipStream_t stream)
{
  (void)in_sizes; (void)n_in; (void)out_size; (void)ws_size;
  const float* in_feats = (const float*)d_in[0];
  const int*   e_src    = (const int*)d_in[1];
  const int*   e_dst    = (const int*)d_in[2];
  const int*   seq      = (const int*)d_in[3];
  const float* W_conv   = (const float*)d_in[4];
  const float* b_conv   = (const float*)d_in[5];
  const float* W_ff1    = (const float*)d_in[6];
  const float* b_ff1    = (const float*)d_in[7];
  const float* W_ih     = (const float*)d_in[8];
  const float* W_hh     = (const float*)d_in[9];
  const float* b_ih     = (const float*)d_in[10];
  const float* b_hh     = (const float*)d_in[11];
  const float* W_ff2    = (const float*)d_in[12];
  const float* b_ff2    = (const float*)d_in[13];

  uint8_t* ws = (uint8_t*)d_ws;
  int*  deg     = (int*) (ws + 0);
  int*  cursor  = (int*) (ws + 262144u);
  int*  roff    = (int*) (ws + 524288u);
  bf16* WcT     = (bf16*)(ws + 1048576u);
  bf16* Wf1T    = (bf16*)(ws + 1572864u);
  bf16* Wf2T    = (bf16*)(ws + 2097152u);
  bf16* WihB    = (bf16*)(ws + 2621440u);
  bf16* WhhB    = (bf16*)(ws + 4194304u);
  int*  csr     = (int*) (ws + 6291456u);
  int*  flags   = (int*) (ws + 10485760u);   // 8*32 ints (monotonic stamps)
  int*  partial = (int*) (ws + 10616832u);   // 64 ints
  int*  sbase   = (int*) (ws + 10620928u);   // 65 ints
  bf16* med2    = (bf16*)(ws + 16777216u);   // 67MB; reused as ys (= h state) after gi GEMM
  bf16* ysb     = med2;
  bf16* gib     = (bf16*)(ws + 83886080u);   // 201MB; aggb/med1/featsb live here pre-gi
  bf16* aggb    = (bf16*)(ws + 83886080u);
  bf16* med1    = (bf16*)(ws + 150994944u);  // also featsb (dead before med1 written)
  bf16* featsb  = (bf16*)(ws + 150994944u);

  hipMemsetAsync(deg,   0, NN * 4,     stream);
  hipMemsetAsync(flags, 0, 8 * 32 * 4, stream);

  k_prep <<<3072, 256, 0, stream>>>(W_conv, W_ff1, W_ff2, W_ih, W_hh, WcT, Wf1T, Wf2T, WihB, WhhB);
  k_cast <<<NN * DD / 1024, 256, 0, stream>>>(in_feats, featsb);
  k_deg  <<<EE / 256, 256, 0, stream>>>(e_dst, deg);
  k_scan1<<<64, 1024, 0, stream>>>(deg, roff, partial);
  k_scan2<<<1, 64, 0, stream>>>(partial, sbase);
  k_scan3<<<64, 1024, 0, stream>>>(sbase, roff, cursor);
  k_fill <<<EE / 256, 256, 0, stream>>>(e_src, e_dst, cursor, csr);
  k_agg  <<<NN, 128, 0, stream>>>(featsb, csr, roff, aggb);

  dim3 g512(4, 512), g1536(12, 512);
  k_gemm<false, false, false><<<g512,  256, 0, stream>>>(aggb, WcT,  b_conv, nullptr, med1, nullptr, 512);
  k_gemm<false, true,  false><<<g512,  256, 0, stream>>>(med1, Wf1T, b_ff1,  nullptr, med2, nullptr, 512);
  k_gemm<true,  false, false><<<g1536, 256, 0, stream>>>(med2, WihB, b_ih,   seq,     gib,  nullptr, 1536);

  k_gru3<<<64, 256, 0, stream>>>(WhhB, b_hh, gib, ysb, flags);

  k_gemm<false, false, true><<<g512, 256, 0, stream>>>(ysb, Wf2T, b_ff2, seq, nullptr, (float*)d_out, 512);
}